// Round 1
// baseline (5447.967 us; speedup 1.0000x reference)
//
#include <hip/hip_runtime.h>
#include <math.h>

// Problem constants (SentenceDecoder): B=64 batch, D=512 word dim, H=1024 hidden,
// V=32000 vocab, L=2 layers, T=32 steps. Gate count NG = 4*H = 4096.
#define BB 64
#define DD 512
#define HH 1024
#define VV 32000
#define NG 4096
#define TT 32
#define NSPLIT 8           // K-split per GEMM for occupancy (64 col-tiles x 8 = 512 blocks)
#define VBLK 500           // V / 64 logits tiles

// ---------------------------------------------------------------------------
// gemm_acc_k: partial C[b][j] = sum_{k in slice} X[b][k] * W[j][k]
// Tile: 64 rows (all of B) x 64 cols, 256 threads, 4x4 micro-tile per thread.
// K split into NSPLIT slices (blockIdx.y); each slice writes its own partial
// buffer (no atomics). K must be divisible by 8*16 (512 and 1024 both are).
// ---------------------------------------------------------------------------
__global__ __launch_bounds__(256)
void gemm_acc_k(const float* __restrict__ X, const float* __restrict__ W,
                int K, float* __restrict__ P)
{
    __shared__ float As[16][68];   // [k][row], pad 68 -> 16B-aligned float4 rows
    __shared__ float Ws[16][68];   // [k][col]

    const int kc  = K >> 3;                       // K / NSPLIT
    const int kk0 = blockIdx.y * kc;
    float* __restrict__ Pout = P + (size_t)blockIdx.y * (BB * NG);
    const int j0 = blockIdx.x * 64;

    const int tid = threadIdx.x;
    const int lk = tid & 15, lr = tid >> 4;       // loader coords
    const int tx = tid & 15, ty = tid >> 4;       // compute coords
    const int r0 = ty * 4, c0 = tx * 4;

    float acc[4][4] = {};

    for (int kb = kk0; kb < kk0 + kc; kb += 16) {
#pragma unroll
        for (int i = 0; i < 4; i++) {
            As[lk][lr + 16 * i] = X[(size_t)(lr + 16 * i) * K + kb + lk];
            Ws[lk][lr + 16 * i] = W[(size_t)(j0 + lr + 16 * i) * K + kb + lk];
        }
        __syncthreads();
#pragma unroll
        for (int kk = 0; kk < 16; kk++) {
            float4 a4 = *(const float4*)&As[kk][r0];
            float4 w4 = *(const float4*)&Ws[kk][c0];
            float av[4] = {a4.x, a4.y, a4.z, a4.w};
            float wv[4] = {w4.x, w4.y, w4.z, w4.w};
#pragma unroll
            for (int i = 0; i < 4; i++)
#pragma unroll
                for (int j = 0; j < 4; j++)
                    acc[i][j] += av[i] * wv[j];
        }
        __syncthreads();
    }

#pragma unroll
    for (int i = 0; i < 4; i++) {
        float4 o = make_float4(acc[i][0], acc[i][1], acc[i][2], acc[i][3]);
        *(float4*)&Pout[(size_t)(r0 + i) * NG + j0 + c0] = o;
    }
}

// ---------------------------------------------------------------------------
// cell_k: sum 16 partial slices + biases -> gates; apply LSTM cell in place.
// Gate order (torch/jax ref): [i, f, g, o] chunks of H.
// ---------------------------------------------------------------------------
__global__ __launch_bounds__(256)
void cell_k(const float* __restrict__ P, const float* __restrict__ bih,
            const float* __restrict__ bhh, float* __restrict__ h,
            float* __restrict__ c)
{
    const int tid = blockIdx.x * 256 + threadIdx.x;   // B*H threads
    const int b = tid >> 10;
    const int u = tid & (HH - 1);

    float gi = bih[u]          + bhh[u];
    float gf = bih[HH + u]     + bhh[HH + u];
    float gg = bih[2 * HH + u] + bhh[2 * HH + u];
    float go = bih[3 * HH + u] + bhh[3 * HH + u];

#pragma unroll
    for (int s = 0; s < 2 * NSPLIT; s++) {
        const float* ps = P + (size_t)s * (BB * NG) + (size_t)b * NG;
        gi += ps[u];
        gf += ps[HH + u];
        gg += ps[2 * HH + u];
        go += ps[3 * HH + u];
    }

    const float si = 1.0f / (1.0f + expf(-gi));
    const float sf = 1.0f / (1.0f + expf(-gf));
    const float so = 1.0f / (1.0f + expf(-go));
    const float cn = sf * c[tid] + si * tanhf(gg);
    const float hn = so * tanhf(cn);
    c[tid] = cn;
    h[tid] = hn;
}

// ---------------------------------------------------------------------------
// logits_k: 64x64 tile of logits = h1 @ Wout^T + bout, K=1024 full, then
// per-block per-row argmax partials (first-occurrence tie-break).
// Grid: 500 blocks.
// ---------------------------------------------------------------------------
__global__ __launch_bounds__(256)
void logits_k(const float* __restrict__ Xh, const float* __restrict__ Wout,
              const float* __restrict__ bout, float* __restrict__ pv,
              int* __restrict__ pi)
{
    __shared__ float As[16][68];
    __shared__ float Ws[16][68];
    __shared__ float rv[64][16];
    __shared__ int   ri[64][16];

    const int v0 = blockIdx.x * 64;
    const int tid = threadIdx.x;
    const int lk = tid & 15, lr = tid >> 4;
    const int tx = tid & 15, ty = tid >> 4;
    const int r0 = ty * 4, c0 = tx * 4;

    float acc[4][4] = {};

    for (int kb = 0; kb < HH; kb += 16) {
#pragma unroll
        for (int i = 0; i < 4; i++) {
            As[lk][lr + 16 * i] = Xh[(size_t)(lr + 16 * i) * HH + kb + lk];
            Ws[lk][lr + 16 * i] = Wout[(size_t)(v0 + lr + 16 * i) * HH + kb + lk];
        }
        __syncthreads();
#pragma unroll
        for (int kk = 0; kk < 16; kk++) {
            float4 a4 = *(const float4*)&As[kk][r0];
            float4 w4 = *(const float4*)&Ws[kk][c0];
            float av[4] = {a4.x, a4.y, a4.z, a4.w};
            float wv[4] = {w4.x, w4.y, w4.z, w4.w};
#pragma unroll
            for (int i = 0; i < 4; i++)
#pragma unroll
                for (int j = 0; j < 4; j++)
                    acc[i][j] += av[i] * wv[j];
        }
        __syncthreads();
    }

    // per-thread argmax over its 4 cols, for each of its 4 rows
#pragma unroll
    for (int i = 0; i < 4; i++) {
        float best = -INFINITY;
        int bid = 0;
#pragma unroll
        for (int j = 0; j < 4; j++) {
            float v = acc[i][j] + bout[v0 + c0 + j];
            if (v > best) { best = v; bid = v0 + c0 + j; }   // ascending j: strict > keeps first
        }
        rv[r0 + i][tx] = best;
        ri[r0 + i][tx] = bid;
    }
    __syncthreads();

    if (tid < 64) {
        float best = -INFINITY;
        int bid = 0;
        for (int k = 0; k < 16; k++) {           // ascending tx == ascending col idx
            float v = rv[tid][k];
            if (v > best) { best = v; bid = ri[tid][k]; }
        }
        pv[(size_t)tid * VBLK + blockIdx.x] = best;
        pi[(size_t)tid * VBLK + blockIdx.x] = bid;
    }
}

// ---------------------------------------------------------------------------
// final_k: reduce 500 argmax partials per row -> pred token; write output id;
// gather embed[pred] into x for the next step. Grid: B blocks.
// ---------------------------------------------------------------------------
__global__ __launch_bounds__(256)
void final_k(const float* __restrict__ pv, const int* __restrict__ pi,
             const float* __restrict__ embed, float* __restrict__ x,
             int* __restrict__ out, int t)
{
    __shared__ float sv[256];
    __shared__ int   si[256];
    const int b = blockIdx.x;
    const int tid = threadIdx.x;

    float best = -INFINITY;
    int bid = 0x7fffffff;
    for (int k = tid; k < VBLK; k += 256) {
        float v = pv[(size_t)b * VBLK + k];
        int id = pi[(size_t)b * VBLK + k];
        if (v > best || (v == best && id < bid)) { best = v; bid = id; }
    }
    sv[tid] = best; si[tid] = bid;
    __syncthreads();
    for (int s = 128; s > 0; s >>= 1) {
        if (tid < s) {
            float v = sv[tid + s]; int id = si[tid + s];
            if (v > sv[tid] || (v == sv[tid] && id < si[tid])) { sv[tid] = v; si[tid] = id; }
        }
        __syncthreads();
    }
    const int pred = si[0];
    if (tid == 0) out[(size_t)b * TT + t] = pred;
    for (int d = tid; d < DD; d += 256)
        x[(size_t)b * DD + d] = embed[(size_t)pred * DD + d];
}

// ---------------------------------------------------------------------------
extern "C" void kernel_launch(void* const* d_in, const int* in_sizes, int n_in,
                              void* d_out, int out_size, void* d_ws, size_t ws_size,
                              hipStream_t stream)
{
    const float* features = (const float*)d_in[0];
    const float* embed    = (const float*)d_in[1];
    const float* Wih0     = (const float*)d_in[2];
    const float* Whh0     = (const float*)d_in[3];
    const float* bih0     = (const float*)d_in[4];
    const float* bhh0     = (const float*)d_in[5];
    const float* Wih1     = (const float*)d_in[6];
    const float* Whh1     = (const float*)d_in[7];
    const float* bih1     = (const float*)d_in[8];
    const float* bhh1     = (const float*)d_in[9];
    const float* Wout     = (const float*)d_in[10];
    const float* bout     = (const float*)d_in[11];
    int* out = (int*)d_out;

    // workspace layout (floats). total ~4.56M floats ~ 18.3 MB.
    float* ws   = (float*)d_ws;
    float* x    = ws;                         // B*D
    float* h0   = x + BB * DD;                // B*H
    float* c0   = h0 + BB * HH;
    float* h1   = c0 + BB * HH;
    float* c1   = h1 + BB * HH;
    float* part = c1 + BB * HH;               // 16 * B * NG
    float* pv   = part + (size_t)2 * NSPLIT * BB * NG;   // B*500
    int*   pi   = (int*)(pv + BB * VBLK);                // B*500

    // zero h0,c0,h1,c1 (contiguous)
    hipMemsetAsync(h0, 0, (size_t)4 * BB * HH * sizeof(float), stream);

    const dim3 blk(256);
    const dim3 ggemm(NG / 64, NSPLIT);
    const dim3 gcell(BB * HH / 256);
    const dim3 glog(VBLK);
    const dim3 gfin(BB);

    for (int t = 0; t < TT; t++) {
        const float* X0 = (t == 0) ? features : x;
        // layer 0
        gemm_acc_k<<<ggemm, blk, 0, stream>>>(X0, Wih0, DD, part);
        gemm_acc_k<<<ggemm, blk, 0, stream>>>(h0, Whh0, HH, part + (size_t)NSPLIT * BB * NG);
        cell_k<<<gcell, blk, 0, stream>>>(part, bih0, bhh0, h0, c0);
        // layer 1
        gemm_acc_k<<<ggemm, blk, 0, stream>>>(h0, Wih1, HH, part);
        gemm_acc_k<<<ggemm, blk, 0, stream>>>(h1, Whh1, HH, part + (size_t)NSPLIT * BB * NG);
        cell_k<<<gcell, blk, 0, stream>>>(part, bih1, bhh1, h1, c1);
        // output projection + argmax partials
        logits_k<<<glog, blk, 0, stream>>>(h1, Wout, bout, pv, pi);
        // argmax reduce + token write + embedding gather
        final_k<<<gfin, blk, 0, stream>>>(pv, pi, embed, x, out, t);
    }
}

// Round 2
// 3095.125 us; speedup vs baseline: 1.7602x; 1.7602x over previous
//
#include <hip/hip_runtime.h>
#include <math.h>

// SentenceDecoder: B=64, D=512, H=1024, V=32000, L=2, T=32. NG = 4H = 4096.
#define BB 64
#define DD 512
#define HH 1024
#define VV 32000
#define NG 4096
#define TT 32
#define NSPLIT 8           // K-split for gate GEMMs
#define VBLK 500           // V / 64 logits tiles

typedef __bf16 bf16x8 __attribute__((ext_vector_type(8)));
typedef float  f32x4  __attribute__((ext_vector_type(4)));

// split fp32 into bf16 hi + bf16 lo (RN-even both): x ~= hi + lo, err ~2^-17 rel
__device__ __forceinline__ void split_bf16(float x, unsigned short* hi, unsigned short* lo)
{
    unsigned u = __float_as_uint(x);
    unsigned r = (u + 0x7fffu + ((u >> 16) & 1u)) & 0xffff0000u;
    *hi = (unsigned short)(r >> 16);
    float rem = x - __uint_as_float(r);
    unsigned u2 = __float_as_uint(rem);
    unsigned r2 = u2 + 0x7fffu + ((u2 >> 16) & 1u);
    *lo = (unsigned short)(r2 >> 16);
}

// ---------------------------------------------------------------------------
// gemm_acc_k: partial C[b][j] = sum_{k in slice} X[b][k] * W[j][k]  (fp32)
// 64x64 tile, 256 threads, 4x4 micro-tile, K split into NSPLIT slices.
// ---------------------------------------------------------------------------
__global__ __launch_bounds__(256)
void gemm_acc_k(const float* __restrict__ X, const float* __restrict__ W,
                int K, float* __restrict__ P)
{
    __shared__ float As[16][68];
    __shared__ float Ws[16][68];

    const int kc  = K >> 3;
    const int kk0 = blockIdx.y * kc;
    float* __restrict__ Pout = P + (size_t)blockIdx.y * (BB * NG);
    const int j0 = blockIdx.x * 64;

    const int tid = threadIdx.x;
    const int lk = tid & 15, lr = tid >> 4;
    const int tx = tid & 15, ty = tid >> 4;
    const int r0 = ty * 4, c0 = tx * 4;

    float acc[4][4] = {};

    for (int kb = kk0; kb < kk0 + kc; kb += 16) {
#pragma unroll
        for (int i = 0; i < 4; i++) {
            As[lk][lr + 16 * i] = X[(size_t)(lr + 16 * i) * K + kb + lk];
            Ws[lk][lr + 16 * i] = W[(size_t)(j0 + lr + 16 * i) * K + kb + lk];
        }
        __syncthreads();
#pragma unroll
        for (int kk = 0; kk < 16; kk++) {
            float4 a4 = *(const float4*)&As[kk][r0];
            float4 w4 = *(const float4*)&Ws[kk][c0];
            float av[4] = {a4.x, a4.y, a4.z, a4.w};
            float wv[4] = {w4.x, w4.y, w4.z, w4.w};
#pragma unroll
            for (int i = 0; i < 4; i++)
#pragma unroll
                for (int j = 0; j < 4; j++)
                    acc[i][j] += av[i] * wv[j];
        }
        __syncthreads();
    }

#pragma unroll
    for (int i = 0; i < 4; i++) {
        float4 o = make_float4(acc[i][0], acc[i][1], acc[i][2], acc[i][3]);
        *(float4*)&Pout[(size_t)(r0 + i) * NG + j0 + c0] = o;
    }
}

// ---------------------------------------------------------------------------
// cell_k: sum partial slices + biases -> gates; LSTM cell; also emit bf16
// hi/lo split of h for the MFMA logits kernel.
// ---------------------------------------------------------------------------
__global__ __launch_bounds__(256)
void cell_k(const float* __restrict__ P, const float* __restrict__ bih,
            const float* __restrict__ bhh, float* __restrict__ h,
            float* __restrict__ c, unsigned short* __restrict__ hhi,
            unsigned short* __restrict__ hlo)
{
    const int tid = blockIdx.x * 256 + threadIdx.x;   // B*H threads
    const int b = tid >> 10;
    const int u = tid & (HH - 1);

    float gi = bih[u]          + bhh[u];
    float gf = bih[HH + u]     + bhh[HH + u];
    float gg = bih[2 * HH + u] + bhh[2 * HH + u];
    float go = bih[3 * HH + u] + bhh[3 * HH + u];

#pragma unroll
    for (int s = 0; s < 2 * NSPLIT; s++) {
        const float* ps = P + (size_t)s * (BB * NG) + (size_t)b * NG;
        gi += ps[u];
        gf += ps[HH + u];
        gg += ps[2 * HH + u];
        go += ps[3 * HH + u];
    }

    const float si = 1.0f / (1.0f + expf(-gi));
    const float sf = 1.0f / (1.0f + expf(-gf));
    const float so = 1.0f / (1.0f + expf(-go));
    const float cn = sf * c[tid] + si * tanhf(gg);
    const float hn = so * tanhf(cn);
    c[tid] = cn;
    h[tid] = hn;
    split_bf16(hn, &hhi[tid], &hlo[tid]);
}

// ---------------------------------------------------------------------------
// logits_mfma_k: 64x64 logits tile via split-bf16 MFMA (3x mfma_16x16x32_bf16
// per tile), argmax-partial epilogue. A (h1) comes pre-split from cell_k;
// W tile converted fp32->hi/lo in-kernel. Grid: 500 blocks x 256 thr (4 waves).
// Wave w computes rows [16w,16w+16) x all 64 cols.
// ---------------------------------------------------------------------------
__global__ __launch_bounds__(256)
void logits_mfma_k(const unsigned short* __restrict__ Ahi,
                   const unsigned short* __restrict__ Alo,
                   const float* __restrict__ Wout,
                   const float* __restrict__ bout,
                   float* __restrict__ pv, int* __restrict__ pi)
{
    // stride 72 bf16 = 144 B per row: 16B-aligned, only 2-way bank aliasing
    __shared__ unsigned short Ah[64][72], Al[64][72], Wh[64][72], Wl[64][72];
    __shared__ float rv[64][16];
    __shared__ int   ri[64][16];

    const int v0   = blockIdx.x * 64;
    const int tid  = threadIdx.x;
    const int wv   = tid >> 6;        // wave id 0..3 -> m rows 16*wv..
    const int lane = tid & 63;
    const int l15  = lane & 15;
    const int q    = lane >> 4;       // quad 0..3

    f32x4 acc[4] = {{0,0,0,0},{0,0,0,0},{0,0,0,0},{0,0,0,0}};

    for (int kb = 0; kb < HH; kb += 64) {
        // stage A hi/lo (already bf16 in global): 2 x uint4 per array per thread
        {
            const int r = tid >> 3;       // 0..31
            const int cc = tid & 7;       // 8-bf16 chunk
#pragma unroll
            for (int qq = 0; qq < 2; qq++) {
                const int row = r + 32 * qq;
                const uint4 vh = *(const uint4*)(Ahi + (size_t)row * HH + kb + cc * 8);
                const uint4 vl = *(const uint4*)(Alo + (size_t)row * HH + kb + cc * 8);
                *(uint4*)&Ah[row][cc * 8] = vh;
                *(uint4*)&Al[row][cc * 8] = vl;
            }
        }
        // stage W: fp32 global -> split bf16 hi/lo in LDS
        {
            const int rr = tid >> 4;      // 0..15
            const int cc = tid & 15;      // 4-fp32 seg
#pragma unroll
            for (int qq = 0; qq < 4; qq++) {
                const int row = rr + 16 * qq;
                float4 w = *(const float4*)(Wout + (size_t)(v0 + row) * HH + kb + cc * 4);
                ushort4 h4, l4;
                split_bf16(w.x, &h4.x, &l4.x);
                split_bf16(w.y, &h4.y, &l4.y);
                split_bf16(w.z, &h4.z, &l4.z);
                split_bf16(w.w, &h4.w, &l4.w);
                *(ushort4*)&Wh[row][cc * 4] = h4;
                *(ushort4*)&Wl[row][cc * 4] = l4;
            }
        }
        __syncthreads();

#pragma unroll
        for (int ks = 0; ks < 2; ks++) {
            const int ko = ks * 32 + q * 8;
            bf16x8 ah = *(const bf16x8*)&Ah[16 * wv + l15][ko];
            bf16x8 al = *(const bf16x8*)&Al[16 * wv + l15][ko];
#pragma unroll
            for (int t = 0; t < 4; t++) {
                bf16x8 bh = *(const bf16x8*)&Wh[16 * t + l15][ko];
                bf16x8 bl = *(const bf16x8*)&Wl[16 * t + l15][ko];
                acc[t] = __builtin_amdgcn_mfma_f32_16x16x32_bf16(ah, bl, acc[t], 0, 0, 0);
                acc[t] = __builtin_amdgcn_mfma_f32_16x16x32_bf16(al, bh, acc[t], 0, 0, 0);
                acc[t] = __builtin_amdgcn_mfma_f32_16x16x32_bf16(ah, bh, acc[t], 0, 0, 0);
            }
        }
        __syncthreads();
    }

    // epilogue: +bias, per-lane argmax over its 4 cols per row, then LDS reduce.
    // C/D layout (16x16): col = lane&15, row = q*4 + reg  [m89-verified]
#pragma unroll
    for (int reg = 0; reg < 4; reg++) {
        float best = -INFINITY;
        int bid = 0x7fffffff;
#pragma unroll
        for (int t = 0; t < 4; t++) {
            const int id = v0 + 16 * t + l15;
            const float v = acc[t][reg] + bout[id];
            if (v > best || (v == best && id < bid)) { best = v; bid = id; }
        }
        rv[16 * wv + q * 4 + reg][l15] = best;
        ri[16 * wv + q * 4 + reg][l15] = bid;
    }
    __syncthreads();

    if (tid < 64) {
        float best = -INFINITY;
        int bid = 0x7fffffff;
        for (int k = 0; k < 16; k++) {
            const float v = rv[tid][k];
            const int id = ri[tid][k];
            if (v > best || (v == best && id < bid)) { best = v; bid = id; }
        }
        pv[(size_t)tid * VBLK + blockIdx.x] = best;
        pi[(size_t)tid * VBLK + blockIdx.x] = bid;
    }
}

// ---------------------------------------------------------------------------
// final_k: reduce VBLK argmax partials per row -> token; gather embed row.
// ---------------------------------------------------------------------------
__global__ __launch_bounds__(256)
void final_k(const float* __restrict__ pv, const int* __restrict__ pi,
             const float* __restrict__ embed, float* __restrict__ x,
             int* __restrict__ out, int t)
{
    __shared__ float sv[256];
    __shared__ int   si[256];
    const int b = blockIdx.x;
    const int tid = threadIdx.x;

    float best = -INFINITY;
    int bid = 0x7fffffff;
    for (int k = tid; k < VBLK; k += 256) {
        float v = pv[(size_t)b * VBLK + k];
        int id = pi[(size_t)b * VBLK + k];
        if (v > best || (v == best && id < bid)) { best = v; bid = id; }
    }
    sv[tid] = best; si[tid] = bid;
    __syncthreads();
    for (int s = 128; s > 0; s >>= 1) {
        if (tid < s) {
            float v = sv[tid + s]; int id = si[tid + s];
            if (v > sv[tid] || (v == sv[tid] && id < si[tid])) { sv[tid] = v; si[tid] = id; }
        }
        __syncthreads();
    }
    const int pred = si[0];
    if (tid == 0) out[(size_t)b * TT + t] = pred;
    for (int d = tid; d < DD; d += 256)
        x[(size_t)b * DD + d] = embed[(size_t)pred * DD + d];
}

// ---------------------------------------------------------------------------
extern "C" void kernel_launch(void* const* d_in, const int* in_sizes, int n_in,
                              void* d_out, int out_size, void* d_ws, size_t ws_size,
                              hipStream_t stream)
{
    const float* features = (const float*)d_in[0];
    const float* embed    = (const float*)d_in[1];
    const float* Wih0     = (const float*)d_in[2];
    const float* Whh0     = (const float*)d_in[3];
    const float* bih0     = (const float*)d_in[4];
    const float* bhh0     = (const float*)d_in[5];
    const float* Wih1     = (const float*)d_in[6];
    const float* Whh1     = (const float*)d_in[7];
    const float* bih1     = (const float*)d_in[8];
    const float* bhh1     = (const float*)d_in[9];
    const float* Wout     = (const float*)d_in[10];
    const float* bout     = (const float*)d_in[11];
    int* out = (int*)d_out;

    float* ws   = (float*)d_ws;
    float* x    = ws;                                     // B*D
    float* h0   = x + BB * DD;                            // B*H each
    float* c0   = h0 + BB * HH;
    float* h1   = c0 + BB * HH;
    float* c1   = h1 + BB * HH;
    float* part = c1 + BB * HH;                           // 2*NSPLIT*B*NG
    float* pv   = part + (size_t)2 * NSPLIT * BB * NG;    // B*VBLK
    int*   pi   = (int*)(pv + BB * VBLK);                 // B*VBLK
    unsigned short* hhi0 = (unsigned short*)(pi + BB * VBLK);   // B*H each
    unsigned short* hlo0 = hhi0 + BB * HH;
    unsigned short* hhi1 = hlo0 + BB * HH;
    unsigned short* hlo1 = hhi1 + BB * HH;

    hipMemsetAsync(h0, 0, (size_t)4 * BB * HH * sizeof(float), stream);

    const dim3 blk(256);
    const dim3 ggemm(NG / 64, NSPLIT);
    const dim3 gcell(BB * HH / 256);
    const dim3 glog(VBLK);
    const dim3 gfin(BB);

    for (int t = 0; t < TT; t++) {
        const float* X0 = (t == 0) ? features : x;
        // layer 0
        gemm_acc_k<<<ggemm, blk, 0, stream>>>(X0, Wih0, DD, part);
        gemm_acc_k<<<ggemm, blk, 0, stream>>>(h0, Whh0, HH, part + (size_t)NSPLIT * BB * NG);
        cell_k<<<gcell, blk, 0, stream>>>(part, bih0, bhh0, h0, c0, hhi0, hlo0);
        // layer 1
        gemm_acc_k<<<ggemm, blk, 0, stream>>>(h0, Wih1, HH, part);
        gemm_acc_k<<<ggemm, blk, 0, stream>>>(h1, Whh1, HH, part + (size_t)NSPLIT * BB * NG);
        cell_k<<<gcell, blk, 0, stream>>>(part, bih1, bhh1, h1, c1, hhi1, hlo1);
        // output projection (split-bf16 MFMA) + argmax partials
        logits_mfma_k<<<glog, blk, 0, stream>>>(hhi1, hlo1, Wout, bout, pv, pi);
        // argmax reduce + token write + embedding gather
        final_k<<<gfin, blk, 0, stream>>>(pv, pi, embed, x, out, t);
    }
}